// Round 1
// baseline (1562.723 us; speedup 1.0000x reference)
//
#include <hip/hip_runtime.h>
#include <math.h>

#define BATCH  512
#define SEQ    2048
#define INPUT  64
#define HID    128
#define LB     8
#define NG     24   // 3 * LB, gate order: r(0:8), z(8:16), n(16:24)

// ---------------------------------------------------------------------------
// Phase 0: fold fc_in + GRU input projection into one 24x64 matrix + bias.
// W_comb[g][i] = sum_h W_ih[g][h] * W_in[h][i]
// b_comb[g]    = b_ih[g] + sum_h W_ih[g][h] * b_in[h] + (g<16 ? b_hh[g] : 0)
//   (b_hh for r,z gates is a plain additive term; b_hh for n stays separate
//    because it is multiplied by r inside tanh.)
// ---------------------------------------------------------------------------
__global__ void precompute_kernel(const float* __restrict__ W_in,
                                  const float* __restrict__ b_in,
                                  const float* __restrict__ W_ih,
                                  const float* __restrict__ b_ih,
                                  const float* __restrict__ b_hh,
                                  float* __restrict__ Wc,   // [24][64]
                                  float* __restrict__ bc)   // [24]
{
    int t = blockIdx.x * blockDim.x + threadIdx.x;
    if (t < NG * INPUT) {
        int g = t / INPUT, i = t % INPUT;
        float acc = 0.f;
        for (int h = 0; h < HID; ++h)
            acc += W_ih[g * HID + h] * W_in[h * INPUT + i];
        Wc[t] = acc;
    } else if (t < NG * INPUT + NG) {
        int g = t - NG * INPUT;
        float acc = b_ih[g];
        if (g < 2 * LB) acc += b_hh[g];
        for (int h = 0; h < HID; ++h)
            acc += W_ih[g * HID + h] * b_in[h];
        bc[g] = acc;
    }
}

// ---------------------------------------------------------------------------
// Phase 1: gates[b][s][g] = A[b][s][:] . Wc[g][:] + bc[g]
// One thread per (b,s). Lane -> consecutive s (tid = b*SEQ + s), so each lane
// streams its own 256B row via float4; L1 merges the 256B-strided accesses.
// Wc/bc are wave-uniform -> compiler emits scalar (s_load) reads.
// ---------------------------------------------------------------------------
__global__ __launch_bounds__(256) void gates_kernel(
    const float* __restrict__ A,     // [B][S][64]
    const float* __restrict__ Wc,    // [24][64]
    const float* __restrict__ bc,    // [24]
    float* __restrict__ gates)       // [B][S][24]
{
    int tid = blockIdx.x * 256 + threadIdx.x;   // = b*SEQ + s
    const float4* a4 = (const float4*)(A + (size_t)tid * INPUT);
    float4 av[16];
#pragma unroll
    for (int i = 0; i < 16; ++i) av[i] = a4[i];

    float out[NG];
#pragma unroll
    for (int g = 0; g < NG; ++g) {
        const float4* w4 = (const float4*)(Wc + g * INPUT);
        float acc = bc[g];
#pragma unroll
        for (int i = 0; i < 16; ++i) {
            float4 w = w4[i];
            acc += av[i].x * w.x + av[i].y * w.y + av[i].z * w.z + av[i].w * w.w;
        }
        out[g] = acc;
    }

    float4* o4 = (float4*)(gates + (size_t)tid * NG);
#pragma unroll
    for (int q = 0; q < 6; ++q)
        o4[q] = make_float4(out[4*q], out[4*q+1], out[4*q+2], out[4*q+3]);
}

// ---------------------------------------------------------------------------
// Phase 2: sequential GRU scan. 64 blocks x 64 threads (1 wave per block).
// Each wave handles 8 batch elements; lane = (batch_in_wave<<3) | hidden_j.
// h vector lives in a 64-float LDS buffer; single-wave DS ops are in-order,
// so no s_barrier is needed (wave_barrier only pins compiler code motion).
// Gate loads are prefetched DPTH steps ahead in a rolling register buffer.
// ---------------------------------------------------------------------------
#define DPTH 16

__global__ __launch_bounds__(64) void scan_kernel(
    const float* __restrict__ gates, // [B][S][24]
    const float* __restrict__ W_hh,  // [24][8]
    const float* __restrict__ b_hh,  // [24]
    float* __restrict__ out)         // [B][8]
{
    const int l  = threadIdx.x;
    const int bl = l >> 3;      // batch element within wave (0..7)
    const int j  = l & 7;       // hidden unit (0..7)
    const int b  = blockIdx.x * 8 + bl;

    // per-lane recurrent weight rows
    float whr[LB], whz[LB], whn[LB];
#pragma unroll
    for (int k = 0; k < LB; ++k) {
        whr[k] = W_hh[(0 * LB + j) * LB + k];
        whz[k] = W_hh[(1 * LB + j) * LB + k];
        whn[k] = W_hh[(2 * LB + j) * LB + k];
    }
    const float bhn = b_hh[2 * LB + j];

    __shared__ float hbuf[64];
    hbuf[l] = 0.f;
    float h_self = 0.f;
    __builtin_amdgcn_wave_barrier();

    const float* gp = gates + (size_t)b * SEQ * NG;

    // prefetch buffers
    float xr[DPTH], xz[DPTH], xn[DPTH];
#pragma unroll
    for (int d = 0; d < DPTH; ++d) {
        xr[d] = gp[d * NG + j];
        xz[d] = gp[d * NG + 8 + j];
        xn[d] = gp[d * NG + 16 + j];
    }

    const float4* hb4 = (const float4*)(&hbuf[bl * 8]);

    for (int s0 = 0; s0 < SEQ; s0 += DPTH) {
#pragma unroll
        for (int d = 0; d < DPTH; ++d) {
            float4 h0 = hb4[0];
            float4 h1 = hb4[1];
            float cxr = xr[d], cxz = xz[d], cxn = xn[d];

            // refill this slot DPTH steps ahead (uniform branch)
            int sp = s0 + d + DPTH;
            if (sp < SEQ) {
                xr[d] = gp[sp * NG + j];
                xz[d] = gp[sp * NG + 8 + j];
                xn[d] = gp[sp * NG + 16 + j];
            }

            // tree-form 8-dots (shorter dep chain than serial FMA)
            float r0 = h0.x * whr[0] + h0.y * whr[1];
            float r1 = h0.z * whr[2] + h0.w * whr[3];
            float r2 = h1.x * whr[4] + h1.y * whr[5];
            float r3 = h1.z * whr[6] + h1.w * whr[7];
            float dr = cxr + ((r0 + r1) + (r2 + r3));

            float z0 = h0.x * whz[0] + h0.y * whz[1];
            float z1 = h0.z * whz[2] + h0.w * whz[3];
            float z2 = h1.x * whz[4] + h1.y * whz[5];
            float z3 = h1.z * whz[6] + h1.w * whz[7];
            float dz = cxz + ((z0 + z1) + (z2 + z3));

            float n0 = h1.x * whn[4] + h1.y * whn[5];
            float n1 = h1.z * whn[6] + h1.w * whn[7];
            float n2 = h0.x * whn[0] + h0.y * whn[1];
            float n3 = h0.z * whn[2] + h0.w * whn[3];
            float dn = bhn + ((n0 + n1) + (n2 + n3));

            float r = 1.f / (1.f + __expf(-dr));
            float z = 1.f / (1.f + __expf(-dz));

            float t = cxn + r * dn;
            t = fminf(fmaxf(t, -15.f), 15.f);   // keep exp finite
            float e  = __expf(-2.f * t);
            float nv = (1.f - e) / (1.f + e);

            h_self = (1.f - z) * nv + z * h_self;

            hbuf[l] = h_self;
            __builtin_amdgcn_wave_barrier();
        }
    }

    out[b * LB + j] = h_self;   // coalesced: out[blockIdx.x*64 + l]
}

// ---------------------------------------------------------------------------
extern "C" void kernel_launch(void* const* d_in, const int* in_sizes, int n_in,
                              void* d_out, int out_size, void* d_ws, size_t ws_size,
                              hipStream_t stream) {
    const float* A    = (const float*)d_in[0];  // (512, 2048, 64)
    const float* W_in = (const float*)d_in[1];  // (128, 64)
    const float* b_in = (const float*)d_in[2];  // (128,)
    const float* W_ih = (const float*)d_in[3];  // (24, 128)
    const float* W_hh = (const float*)d_in[4];  // (24, 8)
    const float* b_ih = (const float*)d_in[5];  // (24,)
    const float* b_hh = (const float*)d_in[6];  // (24,)
    float* out = (float*)d_out;                 // (512, 8)

    // workspace layout: gates [512][2048][24] | Wc [24][64] | bc [24]
    float* gates = (float*)d_ws;
    float* Wc    = gates + (size_t)BATCH * SEQ * NG;
    float* bc    = Wc + NG * INPUT;

    precompute_kernel<<<7, 256, 0, stream>>>(W_in, b_in, W_ih, b_ih, b_hh, Wc, bc);

    gates_kernel<<<(BATCH * SEQ) / 256, 256, 0, stream>>>(A, Wc, bc, gates);

    scan_kernel<<<BATCH / 8, 64, 0, stream>>>(gates, W_hh, b_hh, out);
}

// Round 2
// 1447.812 us; speedup vs baseline: 1.0794x; 1.0794x over previous
//
#include <hip/hip_runtime.h>
#include <math.h>

#define BATCH  512
#define SEQ    2048
#define INPUT  64
#define HID    128
#define LB     8
#define NG     24         // 3 * LB, gate order: r(0:8), z(8:16), n(16:24)
#define GSTRIDE (BATCH * NG)   // floats per timestep-slab in gates[s][b][g]

// ---------------------------------------------------------------------------
// Phase 0: fold fc_in + GRU input projection into one 24x64 matrix + bias.
// W_comb[g][i] = sum_h W_ih[g][h] * W_in[h][i]
// b_comb[g]    = b_ih[g] + sum_h W_ih[g][h]*b_in[h] + (g<16 ? b_hh[g] : 0)
// ---------------------------------------------------------------------------
__global__ void precompute_kernel(const float* __restrict__ W_in,
                                  const float* __restrict__ b_in,
                                  const float* __restrict__ W_ih,
                                  const float* __restrict__ b_ih,
                                  const float* __restrict__ b_hh,
                                  float* __restrict__ Wc,   // [24][64]
                                  float* __restrict__ bc)   // [24]
{
    int t = blockIdx.x * blockDim.x + threadIdx.x;
    if (t < NG * INPUT) {
        int g = t / INPUT, i = t % INPUT;
        float acc = 0.f;
        for (int h = 0; h < HID; ++h)
            acc += W_ih[g * HID + h] * W_in[h * INPUT + i];
        Wc[t] = acc;
    } else if (t < NG * INPUT + NG) {
        int g = t - NG * INPUT;
        float acc = b_ih[g];
        if (g < 2 * LB) acc += b_hh[g];
        for (int h = 0; h < HID; ++h)
            acc += W_ih[g * HID + h] * b_in[h];
        bc[g] = acc;
    }
}

// ---------------------------------------------------------------------------
// Phase 1: gates[s][b][g] = A[b][s][:] . Wc[g][:] + bc[g]   (TRANSPOSED out)
// tid = s*BATCH + b: lanes -> consecutive b. Writes are contiguous 96B/lane
// (coalesced); A reads are 64 rows 512KB apart, merged in L1 across the 16
// float4 loads (16KB wave footprint).
// ---------------------------------------------------------------------------
__global__ __launch_bounds__(256) void gates_kernel(
    const float* __restrict__ A,     // [B][S][64]
    const float* __restrict__ Wc,    // [24][64]
    const float* __restrict__ bc,    // [24]
    float* __restrict__ gates)       // [S][B][24]
{
    int tid = blockIdx.x * 256 + threadIdx.x;   // = s*BATCH + b
    int s = tid >> 9;           // / BATCH
    int b = tid & (BATCH - 1);  // % BATCH

    const float4* a4 = (const float4*)(A + ((size_t)b * SEQ + s) * INPUT);
    float4 av[16];
#pragma unroll
    for (int i = 0; i < 16; ++i) av[i] = a4[i];

    float out[NG];
#pragma unroll
    for (int g = 0; g < NG; ++g) {
        const float4* w4 = (const float4*)(Wc + g * INPUT);
        float acc = bc[g];
#pragma unroll
        for (int i = 0; i < 16; ++i) {
            float4 w = w4[i];
            acc += av[i].x * w.x + av[i].y * w.y + av[i].z * w.z + av[i].w * w.w;
        }
        out[g] = acc;
    }

    float4* o4 = (float4*)(gates + (size_t)tid * NG);
#pragma unroll
    for (int q = 0; q < 6; ++q)
        o4[q] = make_float4(out[4*q], out[4*q+1], out[4*q+2], out[4*q+3]);
}

// ---------------------------------------------------------------------------
// Phase 2: GRU scan with DPP-rotation h-exchange (no LDS on critical path).
//
// Lane map within the wave: lane = row*16 + j*2 + g
//   row = lane>>4 (0..3), j = (lane>>1)&7 (hidden unit), g = lane&1
//   batch b = blockIdx.x*8 + row*2 + g   (8 batches per wave, 64 waves)
// j +/- {1,2,4} == lane rotation by {2,4,8} within the 16-lane DPP row
// (parity g and row preserved). Each lane gathers a rotated full copy of h
// via 7 DPP movs (3 dependent levels, ~VALU latency instead of ~120cy LDS).
// Weight order per slot is resolved AT RUNTIME by pushing (float)j through
// the same DPP sequence, so rotation direction doesn't matter.
// ---------------------------------------------------------------------------
#define DPTH 16

#define ROR2(v)  __int_as_float(__builtin_amdgcn_update_dpp(0, __float_as_int(v), 0x122, 0xF, 0xF, false))
#define ROR4(v)  __int_as_float(__builtin_amdgcn_update_dpp(0, __float_as_int(v), 0x124, 0xF, 0xF, false))
#define ROR8(v)  __int_as_float(__builtin_amdgcn_update_dpp(0, __float_as_int(v), 0x128, 0xF, 0xF, false))

#define GATHER8(sl, x) do {      \
    sl[0] = (x);                 \
    sl[1] = ROR2(sl[0]);         \
    sl[2] = ROR4(sl[0]);         \
    sl[3] = ROR4(sl[1]);         \
    sl[4] = ROR8(sl[0]);         \
    sl[5] = ROR8(sl[1]);         \
    sl[6] = ROR8(sl[2]);         \
    sl[7] = ROR8(sl[3]);         \
} while (0)

__device__ __forceinline__ float dot8(const float* h, const float* w) {
    float d0 = fmaf(h[1], w[1], h[0] * w[0]);
    float d1 = fmaf(h[3], w[3], h[2] * w[2]);
    float d2 = fmaf(h[5], w[5], h[4] * w[4]);
    float d3 = fmaf(h[7], w[7], h[6] * w[6]);
    return (d0 + d1) + (d2 + d3);
}

__global__ __launch_bounds__(64) void scan_kernel(
    const float* __restrict__ gates, // [S][B][24]
    const float* __restrict__ W_hh,  // [24][8]
    const float* __restrict__ b_hh,  // [24]
    float* __restrict__ out)         // [B][8]
{
    const int l   = threadIdx.x;
    const int row = l >> 4;
    const int j   = (l >> 1) & 7;
    const int g   = l & 1;
    const int b   = blockIdx.x * 8 + row * 2 + g;

    // Which hidden index lands in each gathered slot (runtime-resolved):
    float jdx[8];
    GATHER8(jdx, (float)j);

    // Per-slot pre-permuted recurrent weights: slot m holds h[idx[m]],
    // so weight for slot m is W_hh[gate*8 + j][idx[m]].
    float wr[8], wz[8], wn[8];
#pragma unroll
    for (int m = 0; m < 8; ++m) {
        int idx = (int)(jdx[m] + 0.5f);
        wr[m] = W_hh[(0 * LB + j) * LB + idx];
        wz[m] = W_hh[(1 * LB + j) * LB + idx];
        wn[m] = W_hh[(2 * LB + j) * LB + idx];
    }
    const float bhn = b_hh[2 * LB + j];

    // per-lane gate stream base: gates[s][b][{j, 8+j, 16+j}]
    const float* gl = gates + (size_t)b * NG + j;

    float h_self = 0.f;

    // rolling prefetch, DPTH steps deep
    float xr[DPTH], xz[DPTH], xn[DPTH];
#pragma unroll
    for (int d = 0; d < DPTH; ++d) {
        const float* p = gl + (size_t)d * GSTRIDE;
        xr[d] = p[0];
        xz[d] = p[8];
        xn[d] = p[16];
    }

    for (int s0 = 0; s0 < SEQ; s0 += DPTH) {
#pragma unroll
        for (int d = 0; d < DPTH; ++d) {
            float hs[8];
            GATHER8(hs, h_self);

            float cxr = xr[d], cxz = xz[d], cxn = xn[d];

            int sp = s0 + d + DPTH;           // refill DPTH ahead (uniform)
            if (sp < SEQ) {
                const float* p = gl + (size_t)sp * GSTRIDE;
                xr[d] = p[0];
                xz[d] = p[8];
                xn[d] = p[16];
            }

            float dr = cxr + dot8(hs, wr);
            float dz = cxz + dot8(hs, wz);
            float dn = bhn + dot8(hs, wn);

            // sigmoid via v_exp + v_rcp (x->-inf: e=inf, rcp(inf)=0 -> ok)
            float r = __builtin_amdgcn_rcpf(1.f + __expf(-dr));
            float z = __builtin_amdgcn_rcpf(1.f + __expf(-dz));

            float t = fmaf(r, dn, cxn);
            t = fminf(fmaxf(t, -15.f), 15.f);          // keep exp finite
            float e  = __expf(-2.f * t);
            float nv = (1.f - e) * __builtin_amdgcn_rcpf(1.f + e);

            // h = (1-z)*nv + z*h = z*(h - nv) + nv
            h_self = fmaf(z, h_self - nv, nv);
        }
    }

    out[b * LB + j] = h_self;
}

// ---------------------------------------------------------------------------
extern "C" void kernel_launch(void* const* d_in, const int* in_sizes, int n_in,
                              void* d_out, int out_size, void* d_ws, size_t ws_size,
                              hipStream_t stream) {
    const float* A    = (const float*)d_in[0];  // (512, 2048, 64)
    const float* W_in = (const float*)d_in[1];  // (128, 64)
    const float* b_in = (const float*)d_in[2];  // (128,)
    const float* W_ih = (const float*)d_in[3];  // (24, 128)
    const float* W_hh = (const float*)d_in[4];  // (24, 8)
    const float* b_ih = (const float*)d_in[5];  // (24,)
    const float* b_hh = (const float*)d_in[6];  // (24,)
    float* out = (float*)d_out;                 // (512, 8)

    // workspace: gates [2048][512][24] | Wc [24][64] | bc [24]
    float* gates = (float*)d_ws;
    float* Wc    = gates + (size_t)SEQ * BATCH * NG;
    float* bc    = Wc + NG * INPUT;

    precompute_kernel<<<7, 256, 0, stream>>>(W_in, b_in, W_ih, b_ih, b_hh, Wc, bc);

    gates_kernel<<<(BATCH * SEQ) / 256, 256, 0, stream>>>(A, Wc, bc, gates);

    scan_kernel<<<BATCH / 8, 64, 0, stream>>>(gates, W_hh, b_hh, out);
}

// Round 4
// 722.193 us; speedup vs baseline: 2.1639x; 2.0047x over previous
//
#include <hip/hip_runtime.h>
#include <math.h>

#define BATCH  512
#define SEQ    2048
#define INPUT  64
#define HID    128
#define LB     8
#define NG     24              // 3*LB; gates stored as [s][b][j][3] = (r,z,n) per j
#define GSTRIDE (BATCH * NG)   // 12288 floats per timestep-slab
#define T      16              // timesteps per chunk
#define NCHUNK (SEQ / T)       // 128
#define SLABF  (LB * NG)       // 192 floats per 8-batch slab
#define CH_F   (T * SLABF)     // 3072 floats per chunk buffer

// ---------------------------------------------------------------------------
// Phase 0: fold fc_in + GRU input projection into one 24x64 matrix + bias.
// Gate index g: r(0:8), z(8:16), n(16:24)
// ---------------------------------------------------------------------------
__global__ void precompute_kernel(const float* __restrict__ W_in,
                                  const float* __restrict__ b_in,
                                  const float* __restrict__ W_ih,
                                  const float* __restrict__ b_ih,
                                  const float* __restrict__ b_hh,
                                  float* __restrict__ Wc,   // [24][64]
                                  float* __restrict__ bc)   // [24]
{
    int t = blockIdx.x * blockDim.x + threadIdx.x;
    if (t < NG * INPUT) {
        int g = t / INPUT, i = t % INPUT;
        float acc = 0.f;
        for (int h = 0; h < HID; ++h)
            acc += W_ih[g * HID + h] * W_in[h * INPUT + i];
        Wc[t] = acc;
    } else if (t < NG * INPUT + NG) {
        int g = t - NG * INPUT;
        float acc = b_ih[g];
        if (g < 2 * LB) acc += b_hh[g];
        for (int h = 0; h < HID; ++h)
            acc += W_ih[g * HID + h] * b_in[h];
        bc[g] = acc;
    }
}

// ---------------------------------------------------------------------------
// Phase 1: gates[s][b][j][3] = A[b][s][:] . Wc[g][:] + bc[g]
// Tile: 8 b x 16 s per block (128 threads). A staged through LDS (coalesced
// 2KB/instruction global loads); rows padded to 68 floats; 96B/thread
// contiguous writes.
// ---------------------------------------------------------------------------
#define TS 16
#define TB 8

__global__ __launch_bounds__(128) void gates_kernel(
    const float* __restrict__ A,     // [B][S][64]
    const float* __restrict__ Wc,    // [24][64]
    const float* __restrict__ bc,    // [24]
    float* __restrict__ gates)       // [S][B][24]
{
    const int s0 = blockIdx.x * TS;
    const int b0 = blockIdx.y * TB;
    const int tid = threadIdx.x;

    __shared__ float sA[TB * TS * 68];   // 128 rows x 68 floats

#pragma unroll
    for (int it = 0; it < 16; ++it) {
        int f    = it * 128 + tid;       // float4 index over the 32KB tile
        int beta = f >> 8;               // which b
        int rem  = f & 255;
        int srow = rem >> 4;             // s within tile
        int c4   = rem & 15;             // float4 within row
        float4 v = *(const float4*)(A + ((size_t)(b0 + beta) * SEQ + s0 + srow) * INPUT + c4 * 4);
        *(float4*)(&sA[(beta * TS + srow) * 68 + c4 * 4]) = v;
    }
    __syncthreads();

    const int bh = tid & 7;
    const int sh = tid >> 3;
    const float4* row4 = (const float4*)(&sA[(bh * TS + sh) * 68]);
    const float4* Wc4  = (const float4*)Wc;

    float acc[NG];
#pragma unroll
    for (int g = 0; g < NG; ++g) acc[g] = bc[g];

#pragma unroll
    for (int i = 0; i < 16; ++i) {
        float4 a = row4[i];
#pragma unroll
        for (int g = 0; g < NG; ++g) {
            float4 w = Wc4[g * 16 + i];
            acc[g] += a.x * w.x + a.y * w.y + a.z * w.z + a.w * w.w;
        }
    }

    float o[NG];
#pragma unroll
    for (int j = 0; j < LB; ++j) {
        o[j * 3 + 0] = acc[j];
        o[j * 3 + 1] = acc[8 + j];
        o[j * 3 + 2] = acc[16 + j];
    }
    float4* dst = (float4*)(gates + ((size_t)(s0 + sh) * BATCH + b0 + bh) * NG);
#pragma unroll
    for (int q = 0; q < 6; ++q)
        dst[q] = make_float4(o[4*q], o[4*q+1], o[4*q+2], o[4*q+3]);
}

// ---------------------------------------------------------------------------
// Phase 2: GRU scan, producer/consumer wave specialization.
// Block = 128 threads (2 waves), 64 blocks (8 batches each).
//   wave 1 (producer): streams 12KB gate chunks global->regs->LDS, double-
//     buffered, software-pipelined one chunk ahead. No serial dependency, so
//     its 12 independent float4 loads/chunk hide HBM latency.
//   wave 0 (consumer): R2-validated recurrence (DPP h-exchange, rcp gates).
//     Reads its (bh,j) triple from LDS slab at offset (bh*8+j)*3 — the lane
//     permutation is applied at the READ (producer writes natural order).
// One __syncthreads per chunk: producer's chunk c becomes visible for the
// consumer's round c+1; consumer finished buf(c&1) before producer rewrites.
// ---------------------------------------------------------------------------
#define ROR2(v)  __int_as_float(__builtin_amdgcn_update_dpp(0, __float_as_int(v), 0x122, 0xF, 0xF, false))
#define ROR4(v)  __int_as_float(__builtin_amdgcn_update_dpp(0, __float_as_int(v), 0x124, 0xF, 0xF, false))
#define ROR8(v)  __int_as_float(__builtin_amdgcn_update_dpp(0, __float_as_int(v), 0x128, 0xF, 0xF, false))

#define GATHER8(sl, x) do {      \
    sl[0] = (x);                 \
    sl[1] = ROR2(sl[0]);         \
    sl[2] = ROR4(sl[0]);         \
    sl[3] = ROR4(sl[1]);         \
    sl[4] = ROR8(sl[0]);         \
    sl[5] = ROR8(sl[1]);         \
    sl[6] = ROR8(sl[2]);         \
    sl[7] = ROR8(sl[3]);         \
} while (0)

__device__ __forceinline__ float dot8(const float* h, const float* w) {
    float d0 = fmaf(h[1], w[1], h[0] * w[0]);
    float d1 = fmaf(h[3], w[3], h[2] * w[2]);
    float d2 = fmaf(h[5], w[5], h[4] * w[4]);
    float d3 = fmaf(h[7], w[7], h[6] * w[6]);
    return (d0 + d1) + (d2 + d3);
}

__global__ __launch_bounds__(128) void scan_kernel(
    const float* __restrict__ gates, // [S][B][8][3]
    const float* __restrict__ W_hh,  // [24][8]
    const float* __restrict__ b_hh,  // [24]
    float* __restrict__ out)         // [B][8]
{
    __shared__ float sbuf[2 * CH_F];          // 24576 B
    const int tid = threadIdx.x;
    const int wv  = tid >> 6;
    const int l   = tid & 63;
    const int b0  = blockIdx.x * 8;

    if (wv == 1) {
        // ---------------- producer ----------------
        int off_g[12], off_l[12];
#pragma unroll
        for (int w = 0; w < 12; ++w) {
            int q  = w * 64 + l;              // float4 index in chunk, 0..767
            int sw = q / 48;                  // slab (timestep) within chunk
            int rw = q - sw * 48;             // float4 within 192-float slab
            off_g[w] = sw * GSTRIDE + rw * 4; // floats
            off_l[w] = sw * SLABF + rw * 4;   // floats
        }
        const float* gchunk = gates + (size_t)b0 * NG;

        float4 r[12];
#pragma unroll
        for (int w = 0; w < 12; ++w) r[w] = *(const float4*)(gchunk + off_g[w]);
        gchunk += (size_t)T * GSTRIDE;

        for (int c = 0; c < NCHUNK; ++c) {
            float* Ls = &sbuf[(c & 1) * CH_F];
#pragma unroll
            for (int w = 0; w < 12; ++w)
                *(float4*)(Ls + off_l[w]) = r[w];
            if (c + 1 < NCHUNK) {
#pragma unroll
                for (int w = 0; w < 12; ++w)
                    r[w] = *(const float4*)(gchunk + off_g[w]);
                gchunk += (size_t)T * GSTRIDE;
            }
            __syncthreads();                  // round c complete
        }
        __syncthreads();                      // final round (consumer's last chunk)
    } else {
        // ---------------- consumer ----------------
        const int row = l >> 4;
        const int j   = (l >> 1) & 7;
        const int g   = l & 1;
        const int bh  = row * 2 + g;
        const int b   = b0 + bh;
        const int cofs = (bh * LB + j) * 3;   // this lane's triple within a slab

        // slot -> hidden-index map, resolved at runtime through the DPP net
        float jdx[8];
        GATHER8(jdx, (float)j);
        float wr[8], wz[8], wn[8];
#pragma unroll
        for (int m = 0; m < 8; ++m) {
            int idx = (int)(jdx[m] + 0.5f);
            wr[m] = W_hh[(0 * LB + j) * LB + idx];
            wz[m] = W_hh[(1 * LB + j) * LB + idx];
            wn[m] = W_hh[(2 * LB + j) * LB + idx];
        }
        const float bhn = b_hh[2 * LB + j];

        float h = 0.f;
        __syncthreads();                      // round 0: chunk 0 now in buf 0

        for (int c = 1; c <= NCHUNK; ++c) {
            const float* Lb = &sbuf[((c - 1) & 1) * CH_F] + cofs;

            // 2-deep rotating LDS->reg prefetch
            float cr = Lb[0],         cz = Lb[1],         cn = Lb[2];
            float nr = Lb[SLABF + 0], nz = Lb[SLABF + 1], nn = Lb[SLABF + 2];
#pragma unroll
            for (int d = 0; d < T; ++d) {
                float fr = 0.f, fz = 0.f, fn = 0.f;
                if (d + 2 < T) {
                    const float* q = Lb + (d + 2) * SLABF;
                    fr = q[0]; fz = q[1]; fn = q[2];
                }

                float hs[8];
                GATHER8(hs, h);

                float dr = cr + dot8(hs, wr);
                float dz = cz + dot8(hs, wz);
                float dn = bhn + dot8(hs, wn);

                float rr = __builtin_amdgcn_rcpf(1.f + __expf(-dr));
                float zz = __builtin_amdgcn_rcpf(1.f + __expf(-dz));

                float t  = fmaf(rr, dn, cn);
                // tanh(t) = 1 - 2/(1+exp(2t)); endpoint-safe without clamping
                float nv = fmaf(-2.f, __builtin_amdgcn_rcpf(1.f + __expf(2.f * t)), 1.f);

                h = fmaf(zz, h - nv, nv);

                cr = nr; cz = nz; cn = nn;
                nr = fr; nz = fz; nn = fn;
            }
            __syncthreads();
        }

        out[b * LB + j] = h;
    }
}

// ---------------------------------------------------------------------------
extern "C" void kernel_launch(void* const* d_in, const int* in_sizes, int n_in,
                              void* d_out, int out_size, void* d_ws, size_t ws_size,
                              hipStream_t stream) {
    const float* A    = (const float*)d_in[0];  // (512, 2048, 64)
    const float* W_in = (const float*)d_in[1];  // (128, 64)
    const float* b_in = (const float*)d_in[2];  // (128,)
    const float* W_ih = (const float*)d_in[3];  // (24, 128)
    const float* W_hh = (const float*)d_in[4];  // (24, 8)
    const float* b_ih = (const float*)d_in[5];  // (24,)
    const float* b_hh = (const float*)d_in[6];  // (24,)
    float* out = (float*)d_out;                 // (512, 8)

    // workspace: gates [2048][512][24] | Wc [24][64] | bc [24]
    float* gates = (float*)d_ws;
    float* Wc    = gates + (size_t)SEQ * BATCH * NG;
    float* bc    = Wc + NG * INPUT;

    precompute_kernel<<<7, 256, 0, stream>>>(W_in, b_in, W_ih, b_ih, b_hh, Wc, bc);

    dim3 ggrid(SEQ / TS, BATCH / TB);
    gates_kernel<<<ggrid, 128, 0, stream>>>(A, Wc, bc, gates);

    scan_kernel<<<BATCH / 8, 128, 0, stream>>>(gates, W_hh, b_hh, out);
}